// Round 14
// baseline (48.389 us; speedup 1.0000x reference)
//
#include <hip/hip_runtime.h>
#include <hip/hip_bf16.h>
#include <math.h>

// Problem dims (fixed by reference)
#define B_ 16
#define T_ 1024
#define C_ 768
#define H_ 64

typedef __attribute__((ext_vector_type(8))) short bf16x8;
typedef __attribute__((ext_vector_type(4))) short bf16x4;
typedef __attribute__((ext_vector_type(4))) float f32x4;

// fp32 -> bf16 (round-to-nearest-even)
__device__ __forceinline__ short f2bf(float f) {
  union { float f; unsigned u; } un;
  un.f = f;
  unsigned r = un.u + 0x7FFFu + ((un.u >> 16) & 1u);
  return (short)(r >> 16);
}

// ---------------------------------------------------------------------------
// Kernel 1: W prep in 16x16x32 MFMA fragment order (round-9 layout).
// frag f = ks*12 + ct (ks = k-step of 32, 0..23; ct = col-tile of 16, 0..11).
// wfrag[f*512 + l*8 + j] = W_mat[k][col], col=(ct&3)*16+(l&15), mat=ct>>2,
// k = ks*32 + (l>>4)*8 + j.
// ---------------------------------------------------------------------------
__global__ __launch_bounds__(256) void prep_w(
    const float* __restrict__ Wq, const float* __restrict__ Wk,
    const float* __restrict__ Wv, short* __restrict__ wfrag) {
  const int o = blockIdx.x * 256 + threadIdx.x;   // 0..147455
  const int j = o & 7;
  const int l = (o >> 3) & 63;
  const int fid = o >> 9;
  const int ct = fid % 12;
  const int ks = fid / 12;
  const int mat = ct >> 2;
  const int col = (ct & 3) * 16 + (l & 15);
  const int k = ks * 32 + (l >> 4) * 8 + j;
  const float* W = (mat == 0) ? Wq : (mat == 1) ? Wk : Wv;
  wfrag[o] = f2bf(W[(size_t)k * H_ + col]);
}

// ---------------------------------------------------------------------------
// Kernel 2: QKV projection, 16-row tiles -> 1024 blocks (3 blocks/CU = 3
// waves/SIMD with __launch_bounds__(256,3)). 4 waves = 4 K-quarters (192 k =
// 3 chunks of BK=64). x staged via global_load_lds (pre-swizzled source,
// XOR-swz read), 2 bufs, S0+S1 prologue, S2 after chunk-0 compute. W-frag
// loads SPLIT (wf0 then wf1) to cap VGPR < 168. Merge: two-phase pool
// overlapping dead staging; fused qk + V-transpose epilogue.
// ---------------------------------------------------------------------------
#define QKV_LDSF 8192  // floats: 4 waves * 2 bufs * 1024 = 32 KB

__global__ __launch_bounds__(256, 3) void qkv_gemm(
    const float* __restrict__ x, const short* __restrict__ wfrag,
    const float* __restrict__ bq, const float* __restrict__ bk,
    const float* __restrict__ bv,
    short* __restrict__ qk, short* __restrict__ vt) {
  __shared__ float lds[QKV_LDSF];
  const int rt = blockIdx.x;            // 16-row tile (0..1023)
  const int tid = threadIdx.x;
  const int w  = tid >> 6;              // wave = K-quarter
  const int l  = tid & 63;
  const int lo = l & 15, hi = l >> 4;

  float* stg = lds + w * 2048;          // 2 bufs x 1024 floats (4KB each)
  const char* xb = (const char*)(x + (size_t)rt * 16 * C_ + w * 192);

  // stage chunk c (64 k-floats x 16 rows = 4KB): 4 global_load_lds.
  auto STAGE = [&](int buf, int c) {
    #pragma unroll
    for (int s = 0; s < 4; ++s) {
      const int r = s * 4 + hi;
      const char* src = xb + (size_t)r * (C_ * 4) + (size_t)c * 256
                        + ((lo * 16) ^ ((r & 7) << 4));
      float* dst = stg + buf * 1024 + s * 256;  // wave-uniform base
      __builtin_amdgcn_global_load_lds(
          (const __attribute__((address_space(1))) void*)src,
          (__attribute__((address_space(3))) void*)dst, 16, 0, 0);
    }
  };

  f32x4 acc[12];
  #pragma unroll
  for (int ct = 0; ct < 12; ++ct) acc[ct] = (f32x4){0.f, 0.f, 0.f, 0.f};

  STAGE(0, 0);   // chunk 0 -> buf 0
  STAGE(1, 1);   // chunk 1 -> buf 1

  #pragma unroll
  for (int c = 0; c < 3; ++c) {
    const int buf = c & 1;
    const int ksb = w * 6 + c * 2;
    __builtin_amdgcn_sched_barrier(0);
    // ---- first half W-frags (12 coalesced 16B/lane)
    bf16x8 wf0[12];
    #pragma unroll
    for (int ct = 0; ct < 12; ++ct)
      wf0[ct] = *(const bf16x8*)(wfrag + ((size_t)(ksb * 12 + ct) << 9) + l * 8);
    __builtin_amdgcn_sched_barrier(0);
    // ---- wait for THIS chunk's stage (conservative, over-wait-safe)
    if (c < 2) { asm volatile("s_waitcnt vmcnt(16)" ::: "memory"); }
    else       { asm volatile("s_waitcnt vmcnt(12)" ::: "memory"); }
    __builtin_amdgcn_sched_barrier(0);
    // ---- A-frags from LDS (XOR-swz) + cvt
    bf16x8 af0, af1;
    {
      const char* rp = (const char*)(stg + buf * 1024) + lo * 256;
      const int sw = (lo & 7) << 4;
      f32x4 x0 = *(const f32x4*)(rp + ((hi * 32)       ^ sw));
      f32x4 x1 = *(const f32x4*)(rp + ((hi * 32 + 16)  ^ sw));
      f32x4 x2 = *(const f32x4*)(rp + ((128 + hi * 32)      ^ sw));
      f32x4 x3 = *(const f32x4*)(rp + ((128 + hi * 32 + 16) ^ sw));
      #pragma unroll
      for (int j = 0; j < 4; ++j) {
        af0[j] = f2bf(x0[j]); af0[4 + j] = f2bf(x1[j]);
        af1[j] = f2bf(x2[j]); af1[4 + j] = f2bf(x3[j]);
      }
    }
    // ---- compute first k-half
    __builtin_amdgcn_s_setprio(1);
    #pragma unroll
    for (int ct = 0; ct < 12; ++ct)
      acc[ct] = __builtin_amdgcn_mfma_f32_16x16x32_bf16(af0, wf0[ct], acc[ct], 0, 0, 0);
    __builtin_amdgcn_s_setprio(0);
    __builtin_amdgcn_sched_barrier(0);
    // ---- second half W-frags (wf0 registers now dead)
    bf16x8 wf1[12];
    #pragma unroll
    for (int ct = 0; ct < 12; ++ct)
      wf1[ct] = *(const bf16x8*)(wfrag + ((size_t)((ksb + 1) * 12 + ct) << 9) + l * 8);
    __builtin_amdgcn_sched_barrier(0);
    __builtin_amdgcn_s_setprio(1);
    #pragma unroll
    for (int ct = 0; ct < 12; ++ct)
      acc[ct] = __builtin_amdgcn_mfma_f32_16x16x32_bf16(af1, wf1[ct], acc[ct], 0, 0, 0);
    __builtin_amdgcn_s_setprio(0);
    // ---- stage chunk 2 after chunk-0 compute (buf0 reads consumed)
    if (c == 0) {
      __builtin_amdgcn_sched_barrier(0);
      STAGE(0, 2);
    }
  }

  // ---- merge K-quarters: pool[2][16][200] f32 overlaps dead staging
  __syncthreads();
  float* pool = lds;
  if (w < 2) {
    #pragma unroll
    for (int ct = 0; ct < 12; ++ct)
      #pragma unroll
      for (int r = 0; r < 4; ++r)
        pool[w * 3200 + (hi * 4 + r) * 200 + ct * 16 + lo] = acc[ct][r];
  }
  __syncthreads();
  if (w >= 2) {
    #pragma unroll
    for (int ct = 0; ct < 12; ++ct)
      #pragma unroll
      for (int r = 0; r < 4; ++r) {
        float* p = &pool[(w - 2) * 3200 + (hi * 4 + r) * 200 + ct * 16 + lo];
        *p += acc[ct][r];
      }
  }
  __syncthreads();

  // ---- epilogue A: qk (cols 0..127, stride 128). row = tid>>4, 8 cols.
  {
    const int row = tid >> 4;
    const int c0 = (tid & 15) * 8;
    bf16x8 o;
    #pragma unroll
    for (int j = 0; j < 8; ++j) {
      const int col = c0 + j;
      float s = pool[row * 200 + col] + pool[3200 + row * 200 + col];
      s += (col < 64) ? bq[col] : bk[col - 64];
      o[j] = f2bf(s);
    }
    *(bf16x8*)(qk + ((size_t)(rt * 16 + row)) * 128 + c0) = o;
  }
  // ---- epilogue B: fused V-transpose. n = tid>>2, rows (tid&3)*4..+3.
  {
    const int n = tid >> 2;
    const int sub = tid & 3;
    const int b = rt >> 6;
    const int tloc = (rt & 63) * 16;
    const float bias_v = bv[n];
    bf16x4 o;
    #pragma unroll
    for (int j = 0; j < 4; ++j) {
      const int row = sub * 4 + j;
      float s = pool[row * 200 + 128 + n] + pool[3200 + row * 200 + 128 + n];
      o[j] = f2bf(s + bias_v);
    }
    *(bf16x4*)(vt + ((size_t)(b * H_ + n)) * T_ + tloc + sub * 4) = o;
  }
}

// ---------------------------------------------------------------------------
// Kernel 3: flash attention — UNCHANGED round-13-benched version (paired
// q-tiles, 4-way KV-split, swapped QK^T, XCD-aware grid, defer-max).
// ---------------------------------------------------------------------------
#define SCALE_LOG2E 0.18033688011114382f  // 0.125 * log2(e)

__global__ __launch_bounds__(256) void flash(
    const short* __restrict__ qk, const short* __restrict__ vt,
    float* __restrict__ out) {
  __shared__ __align__(16) short p_lds[4][2][16][72];
  __shared__ float o_sh[4][16][64];
  __shared__ float ml_sh[4][2][2][16];  // [wave][tile][m|l][row]

  const int wgid = blockIdx.x;
  const int kk = wgid >> 3;
  const int qp = 31 - (kk & 31);            // big pairs dispatched first
  const int b  = (wgid & 7) + 8 * (kk >> 5);

  const int w = threadIdx.x >> 6;
  const int l = threadIdx.x & 63;
  const int lo = l & 15, hi = l >> 4;
  const int off = hi * 4;

  const int qt0 = 2 * qp, qt1 = 2 * qp + 1;
  const int dtile = qt0 >> 2;
  const int ntot = dtile + 1;
  const int span = (ntot + 3) >> 2;
  const int kv0 = w * span;
  const int kv1 = min(ntot, kv0 + span);
  const int qr0 = qt0 & 3, qr1 = qr0 + 1;

  const short* qrowA = qk + (size_t)(b * T_ + qt0 * 16 + lo) * 128;
  bf16x8 qA0 = *(const bf16x8*)(qrowA + hi * 8);
  bf16x8 qA1 = *(const bf16x8*)(qrowA + 32 + hi * 8);
  const short* qrowB = qk + (size_t)(b * T_ + qt1 * 16 + lo) * 128;
  bf16x8 qB0 = *(const bf16x8*)(qrowB + hi * 8);
  bf16x8 qB1 = *(const bf16x8*)(qrowB + 32 + hi * 8);

  float mA = -1e30f, lsA = 0.f;
  float mB = -1e30f, lsB = 0.f;
  f32x4 oA[4], oB[4];
  #pragma unroll
  for (int dt = 0; dt < 4; ++dt) {
    oA[dt] = (f32x4){0.f, 0.f, 0.f, 0.f};
    oB[dt] = (f32x4){0.f, 0.f, 0.f, 0.f};
  }

  for (int kvt = kv0; kvt < kv1; ++kvt) {
    const bool diag = (kvt == dtile);
    const int nctA = diag ? (qr0 + 1) : 4;
    const int nctB = diag ? (qr1 + 1) : 4;

    bf16x8 kf[8], vf[8];
    #pragma unroll
    for (int ct = 0; ct < 4; ++ct) {
      const short* krow = qk + (size_t)(b * T_ + kvt * 64 + ct * 16 + lo) * 128 + 64;
      kf[2 * ct]     = *(const bf16x8*)(krow + hi * 8);
      kf[2 * ct + 1] = *(const bf16x8*)(krow + 32 + hi * 8);
    }
    #pragma unroll
    for (int dt = 0; dt < 4; ++dt) {
      const short* vrow = vt + (size_t)(b * H_ + dt * 16 + lo) * T_ + kvt * 64;
      vf[2 * dt]     = *(const bf16x8*)(vrow + hi * 8);
      vf[2 * dt + 1] = *(const bf16x8*)(vrow + 32 + hi * 8);
    }

    f32x4 svA[4], svB[4];
    #pragma unroll
    for (int ct = 0; ct < 4; ++ct) {
      svA[ct] = (f32x4){0.f, 0.f, 0.f, 0.f};
      svB[ct] = (f32x4){0.f, 0.f, 0.f, 0.f};
    }
    __builtin_amdgcn_s_setprio(1);
    #pragma unroll
    for (int ct = 0; ct < 4; ++ct) {
      if (ct < nctA) {
        svA[ct] = __builtin_amdgcn_mfma_f32_16x16x32_bf16(kf[2 * ct], qA0, svA[ct], 0, 0, 0);
        svA[ct] = __builtin_amdgcn_mfma_f32_16x16x32_bf16(kf[2 * ct + 1], qA1, svA[ct], 0, 0, 0);
      }
      if (ct < nctB) {
        svB[ct] = __builtin_amdgcn_mfma_f32_16x16x32_bf16(kf[2 * ct], qB0, svB[ct], 0, 0, 0);
        svB[ct] = __builtin_amdgcn_mfma_f32_16x16x32_bf16(kf[2 * ct + 1], qB1, svB[ct], 0, 0, 0);
      }
    }
    __builtin_amdgcn_s_setprio(0);

    #pragma unroll
    for (int ct = 0; ct < 4; ++ct) {
      #pragma unroll
      for (int r = 0; r < 4; ++r) {
        float sA = (ct < nctA) ? svA[ct][r] * SCALE_LOG2E : -1e30f;
        if (diag && ct == qr0 && (off + r) > lo) sA = -1e30f;
        svA[ct][r] = sA;
        float sB = (ct < nctB) ? svB[ct][r] * SCALE_LOG2E : -1e30f;
        if (diag && ct == qr1 && (off + r) > lo) sB = -1e30f;
        svB[ct][r] = sB;
      }
    }

    {
      float tmax = svA[0][0];
      #pragma unroll
      for (int ct = 0; ct < 4; ++ct)
        #pragma unroll
        for (int r = 0; r < 4; ++r) tmax = fmaxf(tmax, svA[ct][r]);
      tmax = fmaxf(tmax, __shfl_xor(tmax, 16));
      tmax = fmaxf(tmax, __shfl_xor(tmax, 32));
      if (!__all(tmax - mA <= 8.0f)) {
        const float mn = fmaxf(mA, tmax);
        const float corr = exp2f(mA - mn);
        mA = mn;
        lsA *= corr;
        #pragma unroll
        for (int r = 0; r < 4; ++r) {
          const float cr = __shfl(corr, off + r);
          #pragma unroll
          for (int dt = 0; dt < 4; ++dt) oA[dt][r] *= cr;
        }
      }
      float psum = 0.f;
      #pragma unroll
      for (int ct = 0; ct < 4; ++ct) {
        #pragma unroll
        for (int r = 0; r < 4; ++r) {
          float p = exp2f(svA[ct][r] - mA);
          svA[ct][r] = p;
          psum += p;
        }
      }
      psum += __shfl_xor(psum, 16);
      psum += __shfl_xor(psum, 32);
      lsA += psum;
      #pragma unroll
      for (int ct = 0; ct < 4; ++ct) {
        __hip_bfloat162 p01 = __float22bfloat162_rn(float2{svA[ct][0], svA[ct][1]});
        __hip_bfloat162 p23 = __float22bfloat162_rn(float2{svA[ct][2], svA[ct][3]});
        uint2 pk;
        pk.x = *reinterpret_cast<unsigned*>(&p01);
        pk.y = *reinterpret_cast<unsigned*>(&p23);
        *reinterpret_cast<uint2*>(&p_lds[w][0][lo][ct * 16 + off]) = pk;
      }
    }
    {
      float tmax = svB[0][0];
      #pragma unroll
      for (int ct = 0; ct < 4; ++ct)
        #pragma unroll
        for (int r = 0; r < 4; ++r) tmax = fmaxf(tmax, svB[ct][r]);
      tmax = fmaxf(tmax, __shfl_xor(tmax, 16));
      tmax = fmaxf(tmax, __shfl_xor(tmax, 32));
      if (!__all(tmax - mB <= 8.0f)) {
        const float mn = fmaxf(mB, tmax);
        const float corr = exp2f(mB - mn);
        mB = mn;
        lsB *= corr;
        #pragma unroll
        for (int r = 0; r < 4; ++r) {
          const float cr = __shfl(corr, off + r);
          #pragma unroll
          for (int dt = 0; dt < 4; ++dt) oB[dt][r] *= cr;
        }
      }
      float psum = 0.f;
      #pragma unroll
      for (int ct = 0; ct < 4; ++ct) {
        #pragma unroll
        for (int r = 0; r < 4; ++r) {
          float p = exp2f(svB[ct][r] - mB);
          svB[ct][r] = p;
          psum += p;
        }
      }
      psum += __shfl_xor(psum, 16);
      psum += __shfl_xor(psum, 32);
      lsB += psum;
      #pragma unroll
      for (int ct = 0; ct < 4; ++ct) {
        __hip_bfloat162 p01 = __float22bfloat162_rn(float2{svB[ct][0], svB[ct][1]});
        __hip_bfloat162 p23 = __float22bfloat162_rn(float2{svB[ct][2], svB[ct][3]});
        uint2 pk;
        pk.x = *reinterpret_cast<unsigned*>(&p01);
        pk.y = *reinterpret_cast<unsigned*>(&p23);
        *reinterpret_cast<uint2*>(&p_lds[w][1][lo][ct * 16 + off]) = pk;
      }
    }

    bf16x8 paA0 = *(const bf16x8*)(&p_lds[w][0][lo][hi * 8]);
    bf16x8 paA1 = *(const bf16x8*)(&p_lds[w][0][lo][32 + hi * 8]);
    bf16x8 paB0 = *(const bf16x8*)(&p_lds[w][1][lo][hi * 8]);
    bf16x8 paB1 = *(const bf16x8*)(&p_lds[w][1][lo][32 + hi * 8]);
    __builtin_amdgcn_s_setprio(1);
    #pragma unroll
    for (int dt = 0; dt < 4; ++dt) {
      oA[dt] = __builtin_amdgcn_mfma_f32_16x16x32_bf16(paA0, vf[2 * dt], oA[dt], 0, 0, 0);
      oA[dt] = __builtin_amdgcn_mfma_f32_16x16x32_bf16(paA1, vf[2 * dt + 1], oA[dt], 0, 0, 0);
      oB[dt] = __builtin_amdgcn_mfma_f32_16x16x32_bf16(paB0, vf[2 * dt], oB[dt], 0, 0, 0);
      oB[dt] = __builtin_amdgcn_mfma_f32_16x16x32_bf16(paB1, vf[2 * dt + 1], oB[dt], 0, 0, 0);
    }
    __builtin_amdgcn_s_setprio(0);
  }

  if (hi == 0) {
    ml_sh[w][0][0][lo] = mA;  ml_sh[w][0][1][lo] = lsA;
    ml_sh[w][1][0][lo] = mB;  ml_sh[w][1][1][lo] = lsB;
  }

  #pragma unroll
  for (int dt = 0; dt < 4; ++dt)
    #pragma unroll
    for (int r = 0; r < 4; ++r)
      o_sh[w][off + r][dt * 16 + lo] = oA[dt][r];
  __syncthreads();
  {
    const int row = threadIdx.x >> 4;
    const int c0 = (threadIdx.x & 15) * 4;
    float M = fmaxf(fmaxf(ml_sh[0][0][0][row], ml_sh[1][0][0][row]),
                    fmaxf(ml_sh[2][0][0][row], ml_sh[3][0][0][row]));
    float e[4];
    float L = 0.f;
    #pragma unroll
    for (int w2 = 0; w2 < 4; ++w2) {
      e[w2] = exp2f(ml_sh[w2][0][0][row] - M);
      L += ml_sh[w2][0][1][row] * e[w2];
    }
    f32x4 o;
    #pragma unroll
    for (int j = 0; j < 4; ++j) {
      float O = 0.f;
      #pragma unroll
      for (int w2 = 0; w2 < 4; ++w2) O += e[w2] * o_sh[w2][row][c0 + j];
      o[j] = O / L;
    }
    *(f32x4*)(out + (size_t)(b * T_ + qt0 * 16 + row) * H_ + c0) = o;
  }
  __syncthreads();
  #pragma unroll
  for (int dt = 0; dt < 4; ++dt)
    #pragma unroll
    for (int r = 0; r < 4; ++r)
      o_sh[w][off + r][dt * 16 + lo] = oB[dt][r];
  __syncthreads();
  {
    const int row = threadIdx.x >> 4;
    const int c0 = (threadIdx.x & 15) * 4;
    float M = fmaxf(fmaxf(ml_sh[0][1][0][row], ml_sh[1][1][0][row]),
                    fmaxf(ml_sh[2][1][0][row], ml_sh[3][1][0][row]));
    float e[4];
    float L = 0.f;
    #pragma unroll
    for (int w2 = 0; w2 < 4; ++w2) {
      e[w2] = exp2f(ml_sh[w2][1][0][row] - M);
      L += ml_sh[w2][1][1][row] * e[w2];
    }
    f32x4 o;
    #pragma unroll
    for (int j = 0; j < 4; ++j) {
      float O = 0.f;
      #pragma unroll
      for (int w2 = 0; w2 < 4; ++w2) O += e[w2] * o_sh[w2][row][c0 + j];
      o[j] = O / L;
    }
    *(f32x4*)(out + (size_t)(b * T_ + qt1 * 16 + row) * H_ + c0) = o;
  }
}

// ---------------------------------------------------------------------------
extern "C" void kernel_launch(void* const* d_in, const int* in_sizes, int n_in,
                              void* d_out, int out_size, void* d_ws, size_t ws_size,
                              hipStream_t stream) {
  const float* x  = (const float*)d_in[0];
  const float* Wq = (const float*)d_in[1];
  const float* bq = (const float*)d_in[2];
  const float* Wk = (const float*)d_in[3];
  const float* bk = (const float*)d_in[4];
  const float* Wv = (const float*)d_in[5];
  const float* bv = (const float*)d_in[6];
  float* out = (float*)d_out;

  // workspace layout (shorts): wfrag | qk (stride 128) | vt
  short* wfrag = (short*)d_ws;
  short* qk = wfrag + (size_t)3 * H_ * C_;           // 147456
  short* vtb = qk + (size_t)B_ * T_ * 128;           // +2097152

  prep_w<<<dim3(576), dim3(256), 0, stream>>>(Wq, Wk, Wv, wfrag);
  qkv_gemm<<<dim3(1024), dim3(256), 0, stream>>>(x, wfrag, bq, bk, bv, qk, vtb);
  flash<<<dim3(512), dim3(256), 0, stream>>>(qk, vtb, out);
}

// Round 15
// 45.904 us; speedup vs baseline: 1.0541x; 1.0541x over previous
//
#include <hip/hip_runtime.h>
#include <hip/hip_bf16.h>
#include <math.h>

// Problem dims (fixed by reference)
#define B_ 16
#define T_ 1024
#define C_ 768
#define H_ 64

typedef __attribute__((ext_vector_type(8))) short bf16x8;
typedef __attribute__((ext_vector_type(4))) float f32x4;
typedef __attribute__((ext_vector_type(16))) float f32x16;

// fp32 -> bf16 (round-to-nearest-even)
__device__ __forceinline__ short f2bf(float f) {
  union { float f; unsigned u; } un;
  un.f = f;
  unsigned r = un.u + 0x7FFFu + ((un.u >> 16) & 1u);
  return (short)(r >> 16);
}

// ---------------------------------------------------------------------------
// Kernel 1: W prep in 32x32x16 MFMA fragment order (round-11 version).
// ---------------------------------------------------------------------------
__global__ __launch_bounds__(256) void prep_w(
    const float* __restrict__ Wq, const float* __restrict__ Wk,
    const float* __restrict__ Wv, short* __restrict__ wfrag) {
  const int o = blockIdx.x * 256 + threadIdx.x;   // 0..147455
  const int j = o & 7;
  const int l = (o >> 3) & 63;
  const int f = o >> 9;                            // 0..287
  const int ct = f % 6;
  const int ks = f / 6;
  const int col = ct * 32 + (l & 31);
  const int mat = col >> 6;
  const int ncol = col & 63;
  const int k = ks * 16 + (l >> 5) * 8 + j;
  const float* W = (mat == 0) ? Wq : (mat == 1) ? Wk : Wv;
  wfrag[o] = f2bf(W[(size_t)k * H_ + ncol]);
}

// ---------------------------------------------------------------------------
// Kernel 2: QKV projection, 32x32x16 MFMA + fused V-transpose epilogue
// (round-11-benched version, restored verbatim).
// ---------------------------------------------------------------------------
#define QKV_LDSF 16384  // floats: 4 waves * 2 bufs * 2048 = 64 KB

__global__ __launch_bounds__(256, 2) void qkv_gemm(
    const float* __restrict__ x, const short* __restrict__ wfrag,
    const float* __restrict__ bq, const float* __restrict__ bk,
    const float* __restrict__ bv,
    short* __restrict__ qk, short* __restrict__ vt) {
  __shared__ float lds[QKV_LDSF];
  const int rt = blockIdx.x;            // 32-row tile
  const int tid = threadIdx.x;
  const int w  = tid >> 6;              // wave = K-quarter
  const int l  = tid & 63;
  const int lo5 = l & 31;               // MFMA row/col lane index
  const int hi1 = l >> 5;               // k-group within frag

  float* stg = lds + w * 4096;          // 2 bufs x 2048 floats (8KB each)
  const char* xb = (const char*)(x + (size_t)rt * 32 * C_ + w * 192);

  auto STAGE = [&](int buf, int c) {
    #pragma unroll
    for (int s = 0; s < 8; ++s) {
      const int row = s * 4 + (l >> 4);
      const char* src = xb + (size_t)row * (C_ * 4) + (size_t)c * 256
                        + (((l & 15) ^ (row & 15)) << 4);
      float* dst = stg + buf * 2048 + s * 256;  // wave-uniform base
      __builtin_amdgcn_global_load_lds(
          (const __attribute__((address_space(1))) void*)src,
          (__attribute__((address_space(3))) void*)dst, 16, 0, 0);
    }
  };

  f32x16 acc[6];
  #pragma unroll
  for (int ct = 0; ct < 6; ++ct)
    #pragma unroll
    for (int r = 0; r < 16; ++r) acc[ct][r] = 0.f;

  STAGE(0, 0);

  #pragma unroll
  for (int c = 0; c < 3; ++c) {
    const int buf = c & 1;
    __builtin_amdgcn_sched_barrier(0);
    // ---- 24 W-frag loads for this chunk
    bf16x8 wf[4][6];
    #pragma unroll
    for (int t = 0; t < 4; ++t)
      #pragma unroll
      for (int ct = 0; ct < 6; ++ct)
        wf[t][ct] = *(const bf16x8*)(wfrag
            + ((size_t)((w * 12 + c * 4 + t) * 6 + ct) << 9) + l * 8);
    __builtin_amdgcn_sched_barrier(0);
    // ---- stage next chunk
    if (c < 2) STAGE(buf ^ 1, c + 1);
    __builtin_amdgcn_sched_barrier(0);
    // ---- wait for THIS chunk's stage only
    if (c < 2) { asm volatile("s_waitcnt vmcnt(32)" ::: "memory"); }
    else       { asm volatile("s_waitcnt vmcnt(24)" ::: "memory"); }
    __builtin_amdgcn_sched_barrier(0);
    // ---- compute: per k-step t: A-frag from LDS (XOR-swz) + cvt + 6 MFMAs
    #pragma unroll
    for (int t = 0; t < 4; ++t) {
      const char* rb = (const char*)(stg + buf * 2048) + lo5 * 256;
      const int m = lo5 & 15;
      const int g0 = t * 4 + hi1 * 2;
      f32x4 x0 = *(const f32x4*)(rb + (((g0)     ^ m) << 4));
      f32x4 x1 = *(const f32x4*)(rb + (((g0 + 1) ^ m) << 4));
      bf16x8 af;
      #pragma unroll
      for (int j = 0; j < 4; ++j) { af[j] = f2bf(x0[j]); af[4 + j] = f2bf(x1[j]); }
      __builtin_amdgcn_s_setprio(1);
      #pragma unroll
      for (int ct = 0; ct < 6; ++ct)
        acc[ct] = __builtin_amdgcn_mfma_f32_32x32x16_bf16(af, wf[t][ct], acc[ct], 0, 0, 0);
      __builtin_amdgcn_s_setprio(0);
    }
  }

  // ---- merge K-quarters: pool[2][32][200] f32 overlaps dead staging region
  __syncthreads();
  float* pool = lds;
  if (w < 2) {
    #pragma unroll
    for (int ct = 0; ct < 6; ++ct)
      #pragma unroll
      for (int r = 0; r < 16; ++r) {
        const int row = (r & 3) + 8 * (r >> 2) + 4 * hi1;
        pool[w * 6400 + row * 200 + ct * 32 + lo5] = acc[ct][r];
      }
  }
  __syncthreads();
  if (w >= 2) {
    #pragma unroll
    for (int ct = 0; ct < 6; ++ct)
      #pragma unroll
      for (int r = 0; r < 16; ++r) {
        const int row = (r & 3) + 8 * (r >> 2) + 4 * hi1;
        float* p = &pool[(w - 2) * 6400 + row * 200 + ct * 32 + lo5];
        *p += acc[ct][r];
      }
  }
  __syncthreads();

  // ---- epilogue A: qk (cols 0..127, stride 128)
  {
    const int row = tid >> 3;
    const int c0 = (tid & 7) * 16;
    bf16x8 o0, o1;
    #pragma unroll
    for (int j = 0; j < 16; ++j) {
      const int col = c0 + j;
      float s = pool[row * 200 + col] + pool[6400 + row * 200 + col];
      s += (col < 64) ? bq[col] : bk[col - 64];
      const short v = f2bf(s);
      if (j < 8) o0[j] = v; else o1[j - 8] = v;
    }
    short* op = qk + ((size_t)(rt * 32 + row)) * 128 + c0;
    *(bf16x8*)(op)     = o0;
    *(bf16x8*)(op + 8) = o1;
  }
  // ---- epilogue B: fused V-transpose
  {
    const int n = tid >> 2;
    const int sub = tid & 3;
    const int b = rt >> 5;
    const int tloc = (rt & 31) * 32;
    const float bias_v = bv[n];
    bf16x8 o;
    #pragma unroll
    for (int j = 0; j < 8; ++j) {
      const int row = sub * 8 + j;
      float s = pool[row * 200 + 128 + n] + pool[6400 + row * 200 + 128 + n];
      o[j] = f2bf(s + bias_v);
    }
    *(bf16x8*)(vt + ((size_t)(b * H_ + n)) * T_ + tloc + sub * 8) = o;
  }
}

// ---------------------------------------------------------------------------
// Kernel 3: flash attention — round-11-benched version restored verbatim
// (paired q-tiles, 4-way KV-split, swapped QK^T, XCD-aware grid, defer-max).
// ---------------------------------------------------------------------------
#define SCALE_LOG2E 0.18033688011114382f  // 0.125 * log2(e)

__global__ __launch_bounds__(256) void flash(
    const short* __restrict__ qk, const short* __restrict__ vt,
    float* __restrict__ out) {
  __shared__ __align__(16) short p_lds[4][2][16][72];
  __shared__ float o_sh[4][16][64];
  __shared__ float ml_sh[4][2][2][16];  // [wave][tile][m|l][row]

  const int wgid = blockIdx.x;
  const int kk = wgid >> 3;
  const int qp = 31 - (kk & 31);            // big pairs dispatched first
  const int b  = (wgid & 7) + 8 * (kk >> 5);

  const int w = threadIdx.x >> 6;
  const int l = threadIdx.x & 63;
  const int lo = l & 15, hi = l >> 4;
  const int off = hi * 4;

  const int qt0 = 2 * qp, qt1 = 2 * qp + 1;
  const int dtile = qt0 >> 2;
  const int ntot = dtile + 1;
  const int span = (ntot + 3) >> 2;
  const int kv0 = w * span;
  const int kv1 = min(ntot, kv0 + span);
  const int qr0 = qt0 & 3, qr1 = qr0 + 1;

  const short* qrowA = qk + (size_t)(b * T_ + qt0 * 16 + lo) * 128;
  bf16x8 qA0 = *(const bf16x8*)(qrowA + hi * 8);
  bf16x8 qA1 = *(const bf16x8*)(qrowA + 32 + hi * 8);
  const short* qrowB = qk + (size_t)(b * T_ + qt1 * 16 + lo) * 128;
  bf16x8 qB0 = *(const bf16x8*)(qrowB + hi * 8);
  bf16x8 qB1 = *(const bf16x8*)(qrowB + 32 + hi * 8);

  float mA = -1e30f, lsA = 0.f;
  float mB = -1e30f, lsB = 0.f;
  f32x4 oA[4], oB[4];
  #pragma unroll
  for (int dt = 0; dt < 4; ++dt) {
    oA[dt] = (f32x4){0.f, 0.f, 0.f, 0.f};
    oB[dt] = (f32x4){0.f, 0.f, 0.f, 0.f};
  }

  for (int kvt = kv0; kvt < kv1; ++kvt) {
    const bool diag = (kvt == dtile);
    const int nctA = diag ? (qr0 + 1) : 4;
    const int nctB = diag ? (qr1 + 1) : 4;

    bf16x8 kf[8], vf[8];
    #pragma unroll
    for (int ct = 0; ct < 4; ++ct) {
      const short* krow = qk + (size_t)(b * T_ + kvt * 64 + ct * 16 + lo) * 128 + 64;
      kf[2 * ct]     = *(const bf16x8*)(krow + hi * 8);
      kf[2 * ct + 1] = *(const bf16x8*)(krow + 32 + hi * 8);
    }
    #pragma unroll
    for (int dt = 0; dt < 4; ++dt) {
      const short* vrow = vt + (size_t)(b * H_ + dt * 16 + lo) * T_ + kvt * 64;
      vf[2 * dt]     = *(const bf16x8*)(vrow + hi * 8);
      vf[2 * dt + 1] = *(const bf16x8*)(vrow + 32 + hi * 8);
    }

    f32x4 svA[4], svB[4];
    #pragma unroll
    for (int ct = 0; ct < 4; ++ct) {
      svA[ct] = (f32x4){0.f, 0.f, 0.f, 0.f};
      svB[ct] = (f32x4){0.f, 0.f, 0.f, 0.f};
    }
    __builtin_amdgcn_s_setprio(1);
    #pragma unroll
    for (int ct = 0; ct < 4; ++ct) {
      if (ct < nctA) {
        svA[ct] = __builtin_amdgcn_mfma_f32_16x16x32_bf16(kf[2 * ct], qA0, svA[ct], 0, 0, 0);
        svA[ct] = __builtin_amdgcn_mfma_f32_16x16x32_bf16(kf[2 * ct + 1], qA1, svA[ct], 0, 0, 0);
      }
      if (ct < nctB) {
        svB[ct] = __builtin_amdgcn_mfma_f32_16x16x32_bf16(kf[2 * ct], qB0, svB[ct], 0, 0, 0);
        svB[ct] = __builtin_amdgcn_mfma_f32_16x16x32_bf16(kf[2 * ct + 1], qB1, svB[ct], 0, 0, 0);
      }
    }
    __builtin_amdgcn_s_setprio(0);

    #pragma unroll
    for (int ct = 0; ct < 4; ++ct) {
      #pragma unroll
      for (int r = 0; r < 4; ++r) {
        float sA = (ct < nctA) ? svA[ct][r] * SCALE_LOG2E : -1e30f;
        if (diag && ct == qr0 && (off + r) > lo) sA = -1e30f;
        svA[ct][r] = sA;
        float sB = (ct < nctB) ? svB[ct][r] * SCALE_LOG2E : -1e30f;
        if (diag && ct == qr1 && (off + r) > lo) sB = -1e30f;
        svB[ct][r] = sB;
      }
    }

    {
      float tmax = svA[0][0];
      #pragma unroll
      for (int ct = 0; ct < 4; ++ct)
        #pragma unroll
        for (int r = 0; r < 4; ++r) tmax = fmaxf(tmax, svA[ct][r]);
      tmax = fmaxf(tmax, __shfl_xor(tmax, 16));
      tmax = fmaxf(tmax, __shfl_xor(tmax, 32));
      if (!__all(tmax - mA <= 8.0f)) {
        const float mn = fmaxf(mA, tmax);
        const float corr = exp2f(mA - mn);
        mA = mn;
        lsA *= corr;
        #pragma unroll
        for (int r = 0; r < 4; ++r) {
          const float cr = __shfl(corr, off + r);
          #pragma unroll
          for (int dt = 0; dt < 4; ++dt) oA[dt][r] *= cr;
        }
      }
      float psum = 0.f;
      #pragma unroll
      for (int ct = 0; ct < 4; ++ct) {
        #pragma unroll
        for (int r = 0; r < 4; ++r) {
          float p = exp2f(svA[ct][r] - mA);
          svA[ct][r] = p;
          psum += p;
        }
      }
      psum += __shfl_xor(psum, 16);
      psum += __shfl_xor(psum, 32);
      lsA += psum;
      #pragma unroll
      for (int ct = 0; ct < 4; ++ct) {
        __hip_bfloat162 p01 = __float22bfloat162_rn(float2{svA[ct][0], svA[ct][1]});
        __hip_bfloat162 p23 = __float22bfloat162_rn(float2{svA[ct][2], svA[ct][3]});
        uint2 pk;
        pk.x = *reinterpret_cast<unsigned*>(&p01);
        pk.y = *reinterpret_cast<unsigned*>(&p23);
        *reinterpret_cast<uint2*>(&p_lds[w][0][lo][ct * 16 + off]) = pk;
      }
    }
    {
      float tmax = svB[0][0];
      #pragma unroll
      for (int ct = 0; ct < 4; ++ct)
        #pragma unroll
        for (int r = 0; r < 4; ++r) tmax = fmaxf(tmax, svB[ct][r]);
      tmax = fmaxf(tmax, __shfl_xor(tmax, 16));
      tmax = fmaxf(tmax, __shfl_xor(tmax, 32));
      if (!__all(tmax - mB <= 8.0f)) {
        const float mn = fmaxf(mB, tmax);
        const float corr = exp2f(mB - mn);
        mB = mn;
        lsB *= corr;
        #pragma unroll
        for (int r = 0; r < 4; ++r) {
          const float cr = __shfl(corr, off + r);
          #pragma unroll
          for (int dt = 0; dt < 4; ++dt) oB[dt][r] *= cr;
        }
      }
      float psum = 0.f;
      #pragma unroll
      for (int ct = 0; ct < 4; ++ct) {
        #pragma unroll
        for (int r = 0; r < 4; ++r) {
          float p = exp2f(svB[ct][r] - mB);
          svB[ct][r] = p;
          psum += p;
        }
      }
      psum += __shfl_xor(psum, 16);
      psum += __shfl_xor(psum, 32);
      lsB += psum;
      #pragma unroll
      for (int ct = 0; ct < 4; ++ct) {
        __hip_bfloat162 p01 = __float22bfloat162_rn(float2{svB[ct][0], svB[ct][1]});
        __hip_bfloat162 p23 = __float22bfloat162_rn(float2{svB[ct][2], svB[ct][3]});
        uint2 pk;
        pk.x = *reinterpret_cast<unsigned*>(&p01);
        pk.y = *reinterpret_cast<unsigned*>(&p23);
        *reinterpret_cast<uint2*>(&p_lds[w][1][lo][ct * 16 + off]) = pk;
      }
    }

    bf16x8 paA0 = *(const bf16x8*)(&p_lds[w][0][lo][hi * 8]);
    bf16x8 paA1 = *(const bf16x8*)(&p_lds[w][0][lo][32 + hi * 8]);
    bf16x8 paB0 = *(const bf16x8*)(&p_lds[w][1][lo][hi * 8]);
    bf16x8 paB1 = *(const bf16x8*)(&p_lds[w][1][lo][32 + hi * 8]);
    __builtin_amdgcn_s_setprio(1);
    #pragma unroll
    for (int dt = 0; dt < 4; ++dt) {
      oA[dt] = __builtin_amdgcn_mfma_f32_16x16x32_bf16(paA0, vf[2 * dt], oA[dt], 0, 0, 0);
      oA[dt] = __builtin_amdgcn_mfma_f32_16x16x32_bf16(paA1, vf[2 * dt + 1], oA[dt], 0, 0, 0);
      oB[dt] = __builtin_amdgcn_mfma_f32_16x16x32_bf16(paB0, vf[2 * dt], oB[dt], 0, 0, 0);
      oB[dt] = __builtin_amdgcn_mfma_f32_16x16x32_bf16(paB1, vf[2 * dt + 1], oB[dt], 0, 0, 0);
    }
    __builtin_amdgcn_s_setprio(0);
  }

  if (hi == 0) {
    ml_sh[w][0][0][lo] = mA;  ml_sh[w][0][1][lo] = lsA;
    ml_sh[w][1][0][lo] = mB;  ml_sh[w][1][1][lo] = lsB;
  }

  #pragma unroll
  for (int dt = 0; dt < 4; ++dt)
    #pragma unroll
    for (int r = 0; r < 4; ++r)
      o_sh[w][off + r][dt * 16 + lo] = oA[dt][r];
  __syncthreads();
  {
    const int row = threadIdx.x >> 4;
    const int c0 = (threadIdx.x & 15) * 4;
    float M = fmaxf(fmaxf(ml_sh[0][0][0][row], ml_sh[1][0][0][row]),
                    fmaxf(ml_sh[2][0][0][row], ml_sh[3][0][0][row]));
    float e[4];
    float L = 0.f;
    #pragma unroll
    for (int w2 = 0; w2 < 4; ++w2) {
      e[w2] = exp2f(ml_sh[w2][0][0][row] - M);
      L += ml_sh[w2][0][1][row] * e[w2];
    }
    f32x4 o;
    #pragma unroll
    for (int j = 0; j < 4; ++j) {
      float O = 0.f;
      #pragma unroll
      for (int w2 = 0; w2 < 4; ++w2) O += e[w2] * o_sh[w2][row][c0 + j];
      o[j] = O / L;
    }
    *(f32x4*)(out + (size_t)(b * T_ + qt0 * 16 + row) * H_ + c0) = o;
  }
  __syncthreads();
  #pragma unroll
  for (int dt = 0; dt < 4; ++dt)
    #pragma unroll
    for (int r = 0; r < 4; ++r)
      o_sh[w][off + r][dt * 16 + lo] = oB[dt][r];
  __syncthreads();
  {
    const int row = threadIdx.x >> 4;
    const int c0 = (threadIdx.x & 15) * 4;
    float M = fmaxf(fmaxf(ml_sh[0][1][0][row], ml_sh[1][1][0][row]),
                    fmaxf(ml_sh[2][1][0][row], ml_sh[3][1][0][row]));
    float e[4];
    float L = 0.f;
    #pragma unroll
    for (int w2 = 0; w2 < 4; ++w2) {
      e[w2] = exp2f(ml_sh[w2][1][0][row] - M);
      L += ml_sh[w2][1][1][row] * e[w2];
    }
    f32x4 o;
    #pragma unroll
    for (int j = 0; j < 4; ++j) {
      float O = 0.f;
      #pragma unroll
      for (int w2 = 0; w2 < 4; ++w2) O += e[w2] * o_sh[w2][row][c0 + j];
      o[j] = O / L;
    }
    *(f32x4*)(out + (size_t)(b * T_ + qt1 * 16 + row) * H_ + c0) = o;
  }
}

// ---------------------------------------------------------------------------
extern "C" void kernel_launch(void* const* d_in, const int* in_sizes, int n_in,
                              void* d_out, int out_size, void* d_ws, size_t ws_size,
                              hipStream_t stream) {
  const float* x  = (const float*)d_in[0];
  const float* Wq = (const float*)d_in[1];
  const float* bq = (const float*)d_in[2];
  const float* Wk = (const float*)d_in[3];
  const float* bk = (const float*)d_in[4];
  const float* Wv = (const float*)d_in[5];
  const float* bv = (const float*)d_in[6];
  float* out = (float*)d_out;

  // workspace layout (shorts): wfrag | qk (stride 128) | vt
  short* wfrag = (short*)d_ws;
  short* qk = wfrag + (size_t)3 * H_ * C_;           // 147456
  short* vtb = qk + (size_t)B_ * T_ * 128;           // +2097152

  prep_w<<<dim3(576), dim3(256), 0, stream>>>(Wq, Wk, Wv, wfrag);
  qkv_gemm<<<dim3(512), dim3(256), 0, stream>>>(x, wfrag, bq, bk, bv, qk, vtb);
  flash<<<dim3(512), dim3(256), 0, stream>>>(qk, vtb, out);
}

// Round 16
// 45.790 us; speedup vs baseline: 1.0568x; 1.0025x over previous
//
#include <hip/hip_runtime.h>
#include <hip/hip_bf16.h>
#include <math.h>

// Problem dims (fixed by reference)
#define B_ 16
#define T_ 1024
#define C_ 768
#define H_ 64

typedef __attribute__((ext_vector_type(8))) short bf16x8;
typedef __attribute__((ext_vector_type(4))) float f32x4;
typedef __attribute__((ext_vector_type(16))) float f32x16;

// fp32 -> bf16 (round-to-nearest-even)
__device__ __forceinline__ short f2bf(float f) {
  union { float f; unsigned u; } un;
  un.f = f;
  unsigned r = un.u + 0x7FFFu + ((un.u >> 16) & 1u);
  return (short)(r >> 16);
}

// ---------------------------------------------------------------------------
// Kernel 1: W prep in 32x32x16 MFMA fragment order (unchanged).
// ---------------------------------------------------------------------------
__global__ __launch_bounds__(256) void prep_w(
    const float* __restrict__ Wq, const float* __restrict__ Wk,
    const float* __restrict__ Wv, short* __restrict__ wfrag) {
  const int o = blockIdx.x * 256 + threadIdx.x;   // 0..147455
  const int j = o & 7;
  const int l = (o >> 3) & 63;
  const int f = o >> 9;                            // 0..287
  const int ct = f % 6;
  const int ks = f / 6;
  const int col = ct * 32 + (l & 31);
  const int mat = col >> 6;
  const int ncol = col & 63;
  const int k = ks * 16 + (l >> 5) * 8 + j;
  const float* W = (mat == 0) ? Wq : (mat == 1) ? Wk : Wv;
  wfrag[o] = f2bf(W[(size_t)k * H_ + ncol]);
}

// ---------------------------------------------------------------------------
// Kernel 2: QKV projection, 32x32x16 MFMA + fused V-transpose epilogue.
// Round-11 structure with ONE reorder: STAGE(c+1) issues BEFORE the W-frag
// loads (HBM fetch starts ~150-300cy earlier; identical vmcnt arithmetic:
// at the wait, outstanding = S(c)[8 oldest] + S(c+1)[8] + W(c)[24] = 40 ->
// vmcnt(32) waits exactly S(c); last chunk vmcnt(24) unchanged).
// ---------------------------------------------------------------------------
#define QKV_LDSF 16384  // floats: 4 waves * 2 bufs * 2048 = 64 KB

__global__ __launch_bounds__(256, 2) void qkv_gemm(
    const float* __restrict__ x, const short* __restrict__ wfrag,
    const float* __restrict__ bq, const float* __restrict__ bk,
    const float* __restrict__ bv,
    short* __restrict__ qk, short* __restrict__ vt) {
  __shared__ float lds[QKV_LDSF];
  const int rt = blockIdx.x;            // 32-row tile
  const int tid = threadIdx.x;
  const int w  = tid >> 6;              // wave = K-quarter
  const int l  = tid & 63;
  const int lo5 = l & 31;               // MFMA row/col lane index
  const int hi1 = l >> 5;               // k-group within frag

  float* stg = lds + w * 4096;          // 2 bufs x 2048 floats (8KB each)
  const char* xb = (const char*)(x + (size_t)rt * 32 * C_ + w * 192);

  auto STAGE = [&](int buf, int c) {
    #pragma unroll
    for (int s = 0; s < 8; ++s) {
      const int row = s * 4 + (l >> 4);
      const char* src = xb + (size_t)row * (C_ * 4) + (size_t)c * 256
                        + (((l & 15) ^ (row & 15)) << 4);
      float* dst = stg + buf * 2048 + s * 256;  // wave-uniform base
      __builtin_amdgcn_global_load_lds(
          (const __attribute__((address_space(1))) void*)src,
          (__attribute__((address_space(3))) void*)dst, 16, 0, 0);
    }
  };

  f32x16 acc[6];
  #pragma unroll
  for (int ct = 0; ct < 6; ++ct)
    #pragma unroll
    for (int r = 0; r < 16; ++r) acc[ct][r] = 0.f;

  STAGE(0, 0);

  #pragma unroll
  for (int c = 0; c < 3; ++c) {
    const int buf = c & 1;
    __builtin_amdgcn_sched_barrier(0);
    // ---- stage next chunk FIRST (HBM fetch starts earliest)
    if (c < 2) STAGE(buf ^ 1, c + 1);
    __builtin_amdgcn_sched_barrier(0);
    // ---- 24 W-frag loads for this chunk
    bf16x8 wf[4][6];
    #pragma unroll
    for (int t = 0; t < 4; ++t)
      #pragma unroll
      for (int ct = 0; ct < 6; ++ct)
        wf[t][ct] = *(const bf16x8*)(wfrag
            + ((size_t)((w * 12 + c * 4 + t) * 6 + ct) << 9) + l * 8);
    __builtin_amdgcn_sched_barrier(0);
    // ---- wait for THIS chunk's stage only (in-order retirement):
    // c<2: outstanding = S(c)[8 oldest] + S(c+1)[8] + W(c)[24] = 40 -> 32
    // c=2: outstanding = S(2)[8 oldest] + W(2)[24] = 32 -> 24
    if (c < 2) { asm volatile("s_waitcnt vmcnt(32)" ::: "memory"); }
    else       { asm volatile("s_waitcnt vmcnt(24)" ::: "memory"); }
    __builtin_amdgcn_sched_barrier(0);
    // ---- compute: per k-step t: A-frag from LDS (XOR-swz) + cvt + 6 MFMAs
    #pragma unroll
    for (int t = 0; t < 4; ++t) {
      const char* rb = (const char*)(stg + buf * 2048) + lo5 * 256;
      const int m = lo5 & 15;
      const int g0 = t * 4 + hi1 * 2;
      f32x4 x0 = *(const f32x4*)(rb + (((g0)     ^ m) << 4));
      f32x4 x1 = *(const f32x4*)(rb + (((g0 + 1) ^ m) << 4));
      bf16x8 af;
      #pragma unroll
      for (int j = 0; j < 4; ++j) { af[j] = f2bf(x0[j]); af[4 + j] = f2bf(x1[j]); }
      __builtin_amdgcn_s_setprio(1);
      #pragma unroll
      for (int ct = 0; ct < 6; ++ct)
        acc[ct] = __builtin_amdgcn_mfma_f32_32x32x16_bf16(af, wf[t][ct], acc[ct], 0, 0, 0);
      __builtin_amdgcn_s_setprio(0);
    }
  }

  // ---- merge K-quarters: pool[2][32][200] f32 overlaps dead staging region
  __syncthreads();
  float* pool = lds;
  if (w < 2) {
    #pragma unroll
    for (int ct = 0; ct < 6; ++ct)
      #pragma unroll
      for (int r = 0; r < 16; ++r) {
        const int row = (r & 3) + 8 * (r >> 2) + 4 * hi1;
        pool[w * 6400 + row * 200 + ct * 32 + lo5] = acc[ct][r];
      }
  }
  __syncthreads();
  if (w >= 2) {
    #pragma unroll
    for (int ct = 0; ct < 6; ++ct)
      #pragma unroll
      for (int r = 0; r < 16; ++r) {
        const int row = (r & 3) + 8 * (r >> 2) + 4 * hi1;
        float* p = &pool[(w - 2) * 6400 + row * 200 + ct * 32 + lo5];
        *p += acc[ct][r];
      }
  }
  __syncthreads();

  // ---- epilogue A: qk (cols 0..127, stride 128)
  {
    const int row = tid >> 3;
    const int c0 = (tid & 7) * 16;
    bf16x8 o0, o1;
    #pragma unroll
    for (int j = 0; j < 16; ++j) {
      const int col = c0 + j;
      float s = pool[row * 200 + col] + pool[6400 + row * 200 + col];
      s += (col < 64) ? bq[col] : bk[col - 64];
      const short v = f2bf(s);
      if (j < 8) o0[j] = v; else o1[j - 8] = v;
    }
    short* op = qk + ((size_t)(rt * 32 + row)) * 128 + c0;
    *(bf16x8*)(op)     = o0;
    *(bf16x8*)(op + 8) = o1;
  }
  // ---- epilogue B: fused V-transpose
  {
    const int n = tid >> 2;
    const int sub = tid & 3;
    const int b = rt >> 5;
    const int tloc = (rt & 31) * 32;
    const float bias_v = bv[n];
    bf16x8 o;
    #pragma unroll
    for (int j = 0; j < 8; ++j) {
      const int row = sub * 8 + j;
      float s = pool[row * 200 + 128 + n] + pool[6400 + row * 200 + 128 + n];
      o[j] = f2bf(s + bias_v);
    }
    *(bf16x8*)(vt + ((size_t)(b * H_ + n)) * T_ + tloc + sub * 8) = o;
  }
}

// ---------------------------------------------------------------------------
// Kernel 3: flash attention — round-11/15-benched version, unchanged
// (paired q-tiles, 4-way KV-split, swapped QK^T, XCD-aware grid, defer-max).
// ---------------------------------------------------------------------------
#define SCALE_LOG2E 0.18033688011114382f  // 0.125 * log2(e)

__global__ __launch_bounds__(256) void flash(
    const short* __restrict__ qk, const short* __restrict__ vt,
    float* __restrict__ out) {
  __shared__ __align__(16) short p_lds[4][2][16][72];
  __shared__ float o_sh[4][16][64];
  __shared__ float ml_sh[4][2][2][16];  // [wave][tile][m|l][row]

  const int wgid = blockIdx.x;
  const int kk = wgid >> 3;
  const int qp = 31 - (kk & 31);            // big pairs dispatched first
  const int b  = (wgid & 7) + 8 * (kk >> 5);

  const int w = threadIdx.x >> 6;
  const int l = threadIdx.x & 63;
  const int lo = l & 15, hi = l >> 4;
  const int off = hi * 4;

  const int qt0 = 2 * qp, qt1 = 2 * qp + 1;
  const int dtile = qt0 >> 2;
  const int ntot = dtile + 1;
  const int span = (ntot + 3) >> 2;
  const int kv0 = w * span;
  const int kv1 = min(ntot, kv0 + span);
  const int qr0 = qt0 & 3, qr1 = qr0 + 1;

  const short* qrowA = qk + (size_t)(b * T_ + qt0 * 16 + lo) * 128;
  bf16x8 qA0 = *(const bf16x8*)(qrowA + hi * 8);
  bf16x8 qA1 = *(const bf16x8*)(qrowA + 32 + hi * 8);
  const short* qrowB = qk + (size_t)(b * T_ + qt1 * 16 + lo) * 128;
  bf16x8 qB0 = *(const bf16x8*)(qrowB + hi * 8);
  bf16x8 qB1 = *(const bf16x8*)(qrowB + 32 + hi * 8);

  float mA = -1e30f, lsA = 0.f;
  float mB = -1e30f, lsB = 0.f;
  f32x4 oA[4], oB[4];
  #pragma unroll
  for (int dt = 0; dt < 4; ++dt) {
    oA[dt] = (f32x4){0.f, 0.f, 0.f, 0.f};
    oB[dt] = (f32x4){0.f, 0.f, 0.f, 0.f};
  }

  for (int kvt = kv0; kvt < kv1; ++kvt) {
    const bool diag = (kvt == dtile);
    const int nctA = diag ? (qr0 + 1) : 4;
    const int nctB = diag ? (qr1 + 1) : 4;

    bf16x8 kf[8], vf[8];
    #pragma unroll
    for (int ct = 0; ct < 4; ++ct) {
      const short* krow = qk + (size_t)(b * T_ + kvt * 64 + ct * 16 + lo) * 128 + 64;
      kf[2 * ct]     = *(const bf16x8*)(krow + hi * 8);
      kf[2 * ct + 1] = *(const bf16x8*)(krow + 32 + hi * 8);
    }
    #pragma unroll
    for (int dt = 0; dt < 4; ++dt) {
      const short* vrow = vt + (size_t)(b * H_ + dt * 16 + lo) * T_ + kvt * 64;
      vf[2 * dt]     = *(const bf16x8*)(vrow + hi * 8);
      vf[2 * dt + 1] = *(const bf16x8*)(vrow + 32 + hi * 8);
    }

    f32x4 svA[4], svB[4];
    #pragma unroll
    for (int ct = 0; ct < 4; ++ct) {
      svA[ct] = (f32x4){0.f, 0.f, 0.f, 0.f};
      svB[ct] = (f32x4){0.f, 0.f, 0.f, 0.f};
    }
    __builtin_amdgcn_s_setprio(1);
    #pragma unroll
    for (int ct = 0; ct < 4; ++ct) {
      if (ct < nctA) {
        svA[ct] = __builtin_amdgcn_mfma_f32_16x16x32_bf16(kf[2 * ct], qA0, svA[ct], 0, 0, 0);
        svA[ct] = __builtin_amdgcn_mfma_f32_16x16x32_bf16(kf[2 * ct + 1], qA1, svA[ct], 0, 0, 0);
      }
      if (ct < nctB) {
        svB[ct] = __builtin_amdgcn_mfma_f32_16x16x32_bf16(kf[2 * ct], qB0, svB[ct], 0, 0, 0);
        svB[ct] = __builtin_amdgcn_mfma_f32_16x16x32_bf16(kf[2 * ct + 1], qB1, svB[ct], 0, 0, 0);
      }
    }
    __builtin_amdgcn_s_setprio(0);

    #pragma unroll
    for (int ct = 0; ct < 4; ++ct) {
      #pragma unroll
      for (int r = 0; r < 4; ++r) {
        float sA = (ct < nctA) ? svA[ct][r] * SCALE_LOG2E : -1e30f;
        if (diag && ct == qr0 && (off + r) > lo) sA = -1e30f;
        svA[ct][r] = sA;
        float sB = (ct < nctB) ? svB[ct][r] * SCALE_LOG2E : -1e30f;
        if (diag && ct == qr1 && (off + r) > lo) sB = -1e30f;
        svB[ct][r] = sB;
      }
    }

    {
      float tmax = svA[0][0];
      #pragma unroll
      for (int ct = 0; ct < 4; ++ct)
        #pragma unroll
        for (int r = 0; r < 4; ++r) tmax = fmaxf(tmax, svA[ct][r]);
      tmax = fmaxf(tmax, __shfl_xor(tmax, 16));
      tmax = fmaxf(tmax, __shfl_xor(tmax, 32));
      if (!__all(tmax - mA <= 8.0f)) {
        const float mn = fmaxf(mA, tmax);
        const float corr = exp2f(mA - mn);
        mA = mn;
        lsA *= corr;
        #pragma unroll
        for (int r = 0; r < 4; ++r) {
          const float cr = __shfl(corr, off + r);
          #pragma unroll
          for (int dt = 0; dt < 4; ++dt) oA[dt][r] *= cr;
        }
      }
      float psum = 0.f;
      #pragma unroll
      for (int ct = 0; ct < 4; ++ct) {
        #pragma unroll
        for (int r = 0; r < 4; ++r) {
          float p = exp2f(svA[ct][r] - mA);
          svA[ct][r] = p;
          psum += p;
        }
      }
      psum += __shfl_xor(psum, 16);
      psum += __shfl_xor(psum, 32);
      lsA += psum;
      #pragma unroll
      for (int ct = 0; ct < 4; ++ct) {
        __hip_bfloat162 p01 = __float22bfloat162_rn(float2{svA[ct][0], svA[ct][1]});
        __hip_bfloat162 p23 = __float22bfloat162_rn(float2{svA[ct][2], svA[ct][3]});
        uint2 pk;
        pk.x = *reinterpret_cast<unsigned*>(&p01);
        pk.y = *reinterpret_cast<unsigned*>(&p23);
        *reinterpret_cast<uint2*>(&p_lds[w][0][lo][ct * 16 + off]) = pk;
      }
    }
    {
      float tmax = svB[0][0];
      #pragma unroll
      for (int ct = 0; ct < 4; ++ct)
        #pragma unroll
        for (int r = 0; r < 4; ++r) tmax = fmaxf(tmax, svB[ct][r]);
      tmax = fmaxf(tmax, __shfl_xor(tmax, 16));
      tmax = fmaxf(tmax, __shfl_xor(tmax, 32));
      if (!__all(tmax - mB <= 8.0f)) {
        const float mn = fmaxf(mB, tmax);
        const float corr = exp2f(mB - mn);
        mB = mn;
        lsB *= corr;
        #pragma unroll
        for (int r = 0; r < 4; ++r) {
          const float cr = __shfl(corr, off + r);
          #pragma unroll
          for (int dt = 0; dt < 4; ++dt) oB[dt][r] *= cr;
        }
      }
      float psum = 0.f;
      #pragma unroll
      for (int ct = 0; ct < 4; ++ct) {
        #pragma unroll
        for (int r = 0; r < 4; ++r) {
          float p = exp2f(svB[ct][r] - mB);
          svB[ct][r] = p;
          psum += p;
        }
      }
      psum += __shfl_xor(psum, 16);
      psum += __shfl_xor(psum, 32);
      lsB += psum;
      #pragma unroll
      for (int ct = 0; ct < 4; ++ct) {
        __hip_bfloat162 p01 = __float22bfloat162_rn(float2{svB[ct][0], svB[ct][1]});
        __hip_bfloat162 p23 = __float22bfloat162_rn(float2{svB[ct][2], svB[ct][3]});
        uint2 pk;
        pk.x = *reinterpret_cast<unsigned*>(&p01);
        pk.y = *reinterpret_cast<unsigned*>(&p23);
        *reinterpret_cast<uint2*>(&p_lds[w][1][lo][ct * 16 + off]) = pk;
      }
    }

    bf16x8 paA0 = *(const bf16x8*)(&p_lds[w][0][lo][hi * 8]);
    bf16x8 paA1 = *(const bf16x8*)(&p_lds[w][0][lo][32 + hi * 8]);
    bf16x8 paB0 = *(const bf16x8*)(&p_lds[w][1][lo][hi * 8]);
    bf16x8 paB1 = *(const bf16x8*)(&p_lds[w][1][lo][32 + hi * 8]);
    __builtin_amdgcn_s_setprio(1);
    #pragma unroll
    for (int dt = 0; dt < 4; ++dt) {
      oA[dt] = __builtin_amdgcn_mfma_f32_16x16x32_bf16(paA0, vf[2 * dt], oA[dt], 0, 0, 0);
      oA[dt] = __builtin_amdgcn_mfma_f32_16x16x32_bf16(paA1, vf[2 * dt + 1], oA[dt], 0, 0, 0);
      oB[dt] = __builtin_amdgcn_mfma_f32_16x16x32_bf16(paB0, vf[2 * dt], oB[dt], 0, 0, 0);
      oB[dt] = __builtin_amdgcn_mfma_f32_16x16x32_bf16(paB1, vf[2 * dt + 1], oB[dt], 0, 0, 0);
    }
    __builtin_amdgcn_s_setprio(0);
  }

  if (hi == 0) {
    ml_sh[w][0][0][lo] = mA;  ml_sh[w][0][1][lo] = lsA;
    ml_sh[w][1][0][lo] = mB;  ml_sh[w][1][1][lo] = lsB;
  }

  #pragma unroll
  for (int dt = 0; dt < 4; ++dt)
    #pragma unroll
    for (int r = 0; r < 4; ++r)
      o_sh[w][off + r][dt * 16 + lo] = oA[dt][r];
  __syncthreads();
  {
    const int row = threadIdx.x >> 4;
    const int c0 = (threadIdx.x & 15) * 4;
    float M = fmaxf(fmaxf(ml_sh[0][0][0][row], ml_sh[1][0][0][row]),
                    fmaxf(ml_sh[2][0][0][row], ml_sh[3][0][0][row]));
    float e[4];
    float L = 0.f;
    #pragma unroll
    for (int w2 = 0; w2 < 4; ++w2) {
      e[w2] = exp2f(ml_sh[w2][0][0][row] - M);
      L += ml_sh[w2][0][1][row] * e[w2];
    }
    f32x4 o;
    #pragma unroll
    for (int j = 0; j < 4; ++j) {
      float O = 0.f;
      #pragma unroll
      for (int w2 = 0; w2 < 4; ++w2) O += e[w2] * o_sh[w2][row][c0 + j];
      o[j] = O / L;
    }
    *(f32x4*)(out + (size_t)(b * T_ + qt0 * 16 + row) * H_ + c0) = o;
  }
  __syncthreads();
  #pragma unroll
  for (int dt = 0; dt < 4; ++dt)
    #pragma unroll
    for (int r = 0; r < 4; ++r)
      o_sh[w][off + r][dt * 16 + lo] = oB[dt][r];
  __syncthreads();
  {
    const int row = threadIdx.x >> 4;
    const int c0 = (threadIdx.x & 15) * 4;
    float M = fmaxf(fmaxf(ml_sh[0][1][0][row], ml_sh[1][1][0][row]),
                    fmaxf(ml_sh[2][1][0][row], ml_sh[3][1][0][row]));
    float e[4];
    float L = 0.f;
    #pragma unroll
    for (int w2 = 0; w2 < 4; ++w2) {
      e[w2] = exp2f(ml_sh[w2][1][0][row] - M);
      L += ml_sh[w2][1][1][row] * e[w2];
    }
    f32x4 o;
    #pragma unroll
    for (int j = 0; j < 4; ++j) {
      float O = 0.f;
      #pragma unroll
      for (int w2 = 0; w2 < 4; ++w2) O += e[w2] * o_sh[w2][row][c0 + j];
      o[j] = O / L;
    }
    *(f32x4*)(out + (size_t)(b * T_ + qt1 * 16 + row) * H_ + c0) = o;
  }
}

// ---------------------------------------------------------------------------
extern "C" void kernel_launch(void* const* d_in, const int* in_sizes, int n_in,
                              void* d_out, int out_size, void* d_ws, size_t ws_size,
                              hipStream_t stream) {
  const float* x  = (const float*)d_in[0];
  const float* Wq = (const float*)d_in[1];
  const float* bq = (const float*)d_in[2];
  const float* Wk = (const float*)d_in[3];
  const float* bk = (const float*)d_in[4];
  const float* Wv = (const float*)d_in[5];
  const float* bv = (const float*)d_in[6];
  float* out = (float*)d_out;

  // workspace layout (shorts): wfrag | qk (stride 128) | vt
  short* wfrag = (short*)d_ws;
  short* qk = wfrag + (size_t)3 * H_ * C_;           // 147456
  short* vtb = qk + (size_t)B_ * T_ * 128;           // +2097152

  prep_w<<<dim3(576), dim3(256), 0, stream>>>(Wq, Wk, Wv, wfrag);
  qkv_gemm<<<dim3(512), dim3(256), 0, stream>>>(x, wfrag, bq, bk, bv, qk, vtb);
  flash<<<dim3(512), dim3(256), 0, stream>>>(qk, vtb, out);
}